// Round 1
// baseline (4170.236 us; speedup 1.0000x reference)
//
#include <hip/hip_runtime.h>

#define HDIM 64
#define STEPS 3

// ---------------- embed: x[i] = emb[tokens[i]] ----------------
__global__ __launch_bounds__(256) void k_embed(const int* __restrict__ tokens,
                                               const float* __restrict__ emb,
                                               float* __restrict__ x, int n) {
  int i = blockIdx.x * 256 + threadIdx.x;
  if (i < n * HDIM) {
    int node = i >> 6;
    int h = i & 63;
    x[i] = emb[tokens[node] * HDIM + h];
  }
}

// ---------------- m = x @ W   (W row-major [k][j], 64x64) ----------------
// One wave per 8 rows; W staged in LDS; x row broadcast via shuffles.
__global__ __launch_bounds__(256) void k_xform(const float* __restrict__ x,
                                               const float* __restrict__ W,
                                               float* __restrict__ m, int n) {
  __shared__ float Ws[HDIM * HDIM];
  for (int t = threadIdx.x; t < HDIM * HDIM; t += 256) Ws[t] = W[t];
  __syncthreads();
  const int lane = threadIdx.x & 63;
  const int wave = threadIdx.x >> 6;
  const int RPW = 8;
  int row0 = (blockIdx.x * 4 + wave) * RPW;
  for (int r = 0; r < RPW; ++r) {
    int row = row0 + r;
    if (row >= n) return;
    float xv = x[row * HDIM + lane];
    float acc = 0.f;
#pragma unroll
    for (int k = 0; k < HDIM; ++k) {
      acc = fmaf(__shfl(xv, k), Ws[k * HDIM + lane], acc);
    }
    m[row * HDIM + lane] = acc;
  }
}

// ---------------- agg[dst] += m[src] over edges (atomic) ----------------
// One wave per edge-quad; lane = channel. Reads/atomics are per-channel
// coalesced 256B rows at random node offsets (L2/L3 resident).
__global__ __launch_bounds__(256) void k_scatter(const int* __restrict__ srcs,
                                                 const int* __restrict__ dsts,
                                                 const float* __restrict__ m,
                                                 float* __restrict__ agg, int ne) {
  const int lane = threadIdx.x & 63;
  int gw = (blockIdx.x * 256 + threadIdx.x) >> 6;
  int e0 = gw * 4;
#pragma unroll
  for (int i = 0; i < 4; ++i) {
    int e = e0 + i;
    if (e < ne) {
      int s = srcs[e];
      int d = dsts[e];
      atomicAdd(&agg[d * HDIM + lane], m[s * HDIM + lane]);
    }
  }
}

// ---------------- GRU cell: x = GRU(agg, x) ----------------
// 1024 threads = 16 waves, one node per wave. Weights transposed into LDS
// so lane j reads wT[k*192 + gate*64 + j] (stride-1 -> conflict-free).
__global__ __launch_bounds__(1024) void k_gru(const float* __restrict__ agg,
                                              float* __restrict__ x,
                                              const float* __restrict__ w_ih,
                                              const float* __restrict__ w_hh,
                                              const float* __restrict__ b_ih,
                                              const float* __restrict__ b_hh,
                                              int n) {
  __shared__ float wiT[HDIM * 3 * HDIM];  // [k][j]  j in 0..191
  __shared__ float whT[HDIM * 3 * HDIM];
  __shared__ float bi[3 * HDIM], bh[3 * HDIM];
  for (int t = threadIdx.x; t < HDIM * 3 * HDIM; t += 1024) {
    int k = t / (3 * HDIM);
    int j = t % (3 * HDIM);
    wiT[t] = w_ih[j * HDIM + k];
    whT[t] = w_hh[j * HDIM + k];
  }
  for (int t = threadIdx.x; t < 3 * HDIM; t += 1024) {
    bi[t] = b_ih[t];
    bh[t] = b_hh[t];
  }
  __syncthreads();

  const int lane = threadIdx.x & 63;
  const int wid = threadIdx.x >> 6;  // 0..15
  int node = blockIdx.x * 16 + wid;
  if (node >= n) return;

  float av = agg[node * HDIM + lane];
  float xv = x[node * HDIM + lane];

  float gi_r = bi[lane], gi_z = bi[64 + lane], gi_n = bi[128 + lane];
  float gh_r = bh[lane], gh_z = bh[64 + lane], gh_n = bh[128 + lane];
#pragma unroll
  for (int k = 0; k < HDIM; ++k) {
    float a = __shfl(av, k);
    float h = __shfl(xv, k);
    const float* wk = &wiT[k * 192];
    const float* vk = &whT[k * 192];
    gi_r = fmaf(a, wk[lane], gi_r);
    gi_z = fmaf(a, wk[64 + lane], gi_z);
    gi_n = fmaf(a, wk[128 + lane], gi_n);
    gh_r = fmaf(h, vk[lane], gh_r);
    gh_z = fmaf(h, vk[64 + lane], gh_z);
    gh_n = fmaf(h, vk[128 + lane], gh_n);
  }
  float r = 1.f / (1.f + __expf(-(gi_r + gh_r)));
  float z = 1.f / (1.f + __expf(-(gi_z + gh_z)));
  float nn = tanhf(gi_n + r * gh_n);
  x[node * HDIM + lane] = (1.f - z) * nn + z * xv;
}

// ---------------- per-graph mean pool of relu(x); batch sorted ----------------
__device__ __forceinline__ int lower_bound_i(const int* __restrict__ a, int n, int v) {
  int lo = 0, hi = n;
  while (lo < hi) {
    int mid = (lo + hi) >> 1;
    if (a[mid] < v) lo = mid + 1; else hi = mid;
  }
  return lo;
}

__global__ __launch_bounds__(256) void k_pool(const float* __restrict__ x,
                                              const int* __restrict__ batch,
                                              float* __restrict__ pooled,
                                              int n) {
  int g = blockIdx.x;
  int lo = lower_bound_i(batch, n, g);
  int hi = lower_bound_i(batch, n, g + 1);
  const int lane = threadIdx.x & 63;
  const int w = threadIdx.x >> 6;  // 0..3
  float acc = 0.f;
  for (int i = lo + w; i < hi; i += 4) {
    acc += fmaxf(x[i * HDIM + lane], 0.f);
  }
  __shared__ float red[4][HDIM];
  red[w][lane] = acc;
  __syncthreads();
  if (w == 0) {
    float s = red[0][lane] + red[1][lane] + red[2][lane] + red[3][lane];
    float cnt = (float)(hi - lo);
    pooled[g * HDIM + lane] = s / fmaxf(cnt, 1.f);
  }
}

// ---------------- head: out = relu(pooled@lin1_w.T+b1) @ lout_w.T + b2 ----------------
__global__ __launch_bounds__(256) void k_head(const float* __restrict__ pooled,
                                              const float* __restrict__ lin1_w,
                                              const float* __restrict__ lin1_b,
                                              const float* __restrict__ lout_w,
                                              const float* __restrict__ lout_b,
                                              float* __restrict__ out, int G) {
  __shared__ float P[128 * HDIM];
  __shared__ float W1T[HDIM * HDIM];  // [k][j]
  __shared__ float H1[128 * HDIM];
  for (int t = threadIdx.x; t < G * HDIM; t += 256) P[t] = pooled[t];
  for (int t = threadIdx.x; t < HDIM * HDIM; t += 256) {
    int j = t & 63, k = t >> 6;
    W1T[k * HDIM + j] = lin1_w[j * HDIM + k];
  }
  __syncthreads();
  for (int idx = threadIdx.x; idx < G * HDIM; idx += 256) {
    int g = idx >> 6, j = idx & 63;
    float acc = lin1_b[j];
#pragma unroll
    for (int k = 0; k < HDIM; ++k) acc = fmaf(P[g * HDIM + k], W1T[k * HDIM + j], acc);
    H1[idx] = fmaxf(acc, 0.f);
  }
  __syncthreads();
  for (int idx = threadIdx.x; idx < G * 2; idx += 256) {
    int g = idx >> 1, c = idx & 1;
    float acc = lout_b[c];
#pragma unroll
    for (int j = 0; j < HDIM; ++j) acc = fmaf(H1[g * HDIM + j], lout_w[c * HDIM + j], acc);
    out[idx] = acc;
  }
}

extern "C" void kernel_launch(void* const* d_in, const int* in_sizes, int n_in,
                              void* d_out, int out_size, void* d_ws, size_t ws_size,
                              hipStream_t stream) {
  const int* tokens   = (const int*)d_in[0];
  const int* edge_idx = (const int*)d_in[1];
  const int* batch    = (const int*)d_in[2];
  const float* emb    = (const float*)d_in[3];
  const float* ggnn_w = (const float*)d_in[4];
  const float* w_ih   = (const float*)d_in[5];
  const float* w_hh   = (const float*)d_in[6];
  const float* b_ih   = (const float*)d_in[7];
  const float* b_hh   = (const float*)d_in[8];
  const float* lin1_w = (const float*)d_in[9];
  const float* lin1_b = (const float*)d_in[10];
  const float* lout_w = (const float*)d_in[11];
  const float* lout_b = (const float*)d_in[12];

  const int N = in_sizes[0];
  const int E = in_sizes[1] / 2;
  const int G = out_size / 2;

  const int* srcs = edge_idx;
  const int* dsts = edge_idx + E;

  char* ws = (char*)d_ws;
  size_t rowBytes = (size_t)N * HDIM * sizeof(float);
  float* x    = (float*)(ws);
  float* m    = (float*)(ws + rowBytes);
  float* agg  = (float*)(ws + 2 * rowBytes);
  float* pooled = (float*)(ws + 3 * rowBytes);

  // embed
  {
    int total = N * HDIM;
    k_embed<<<(total + 255) / 256, 256, 0, stream>>>(tokens, emb, x, N);
  }

  for (int s = 0; s < STEPS; ++s) {
    const float* W = ggnn_w + (size_t)s * HDIM * HDIM;
    int xblocks = (N + 31) / 32;  // 4 waves * 8 rows per block
    k_xform<<<xblocks, 256, 0, stream>>>(x, W, m, N);
    hipMemsetAsync(agg, 0, rowBytes, stream);
    int sblocks = (E + 15) / 16;  // 4 waves * 4 edges per block
    k_scatter<<<sblocks, 256, 0, stream>>>(srcs, dsts, m, agg, E);
    int gblocks = (N + 15) / 16;
    k_gru<<<gblocks, 1024, 0, stream>>>(agg, x, w_ih, w_hh, b_ih, b_hh, N);
  }

  k_pool<<<G, 256, 0, stream>>>(x, batch, pooled, N);
  k_head<<<1, 256, 0, stream>>>(pooled, lin1_w, lin1_b, lout_w, lout_b,
                                (float*)d_out, G);
}